// Round 1
// baseline (113.907 us; speedup 1.0000x reference)
//
#include <hip/hip_runtime.h>

// MoE all-experts dense MLP, fused bf16-MFMA kernel.
// E=8, D_IN=128, D_HID=256, D_OUT=128, B=65536. Out f32 [B,128].

#define E_    8
#define DIN_  128
#define DH_   256
#define DOUT_ 128
#define BM_   256   // batch rows per block

typedef __attribute__((ext_vector_type(8))) short bf16x8;  // 8 bf16 = 4 VGPR (MFMA A/B frag)
typedef __attribute__((ext_vector_type(4))) float f32x4;   // MFMA C/D frag

__device__ __forceinline__ unsigned short f2bf(float f) {
  union { float f; unsigned int u; } v; v.f = f;
  unsigned int u = v.u;
  u += 0x7fffu + ((u >> 16) & 1u);   // round-to-nearest-even
  return (unsigned short)(u >> 16);
}

__device__ __forceinline__ void gload_lds16(const void* g, void* l) {
  // async global->LDS, 16B per lane; LDS dest = wave-uniform base + lane*16
  __builtin_amdgcn_global_load_lds(
      (const __attribute__((address_space(1))) unsigned int*)g,
      (__attribute__((address_space(3))) unsigned int*)l, 16, 0, 0);
}

// ---------------- prep: f32 [mats][R][C] -> bf16 [mats][C][R] ----------------
__global__ __launch_bounds__(256) void transpose_to_bf16(
    const float* __restrict__ in, unsigned short* __restrict__ out,
    int R, int C, int nTR, int nTC)
{
  __shared__ float tile[64][65];
  const int tiles = nTR * nTC;
  const int mat = blockIdx.x / tiles;
  const int tt  = blockIdx.x % tiles;
  const int tr = tt / nTC, tc = tt % nTC;
  const float* src = in + (size_t)mat * R * C;
  unsigned short* dst = out + (size_t)mat * R * C;
  const int tid = threadIdx.x;
  #pragma unroll
  for (int i = 0; i < 16; ++i) {
    int row = i * 4 + (tid >> 6);
    int col = tid & 63;
    tile[row][col] = src[(size_t)(tr * 64 + row) * C + tc * 64 + col];
  }
  __syncthreads();
  #pragma unroll
  for (int i = 0; i < 8; ++i) {
    int c  = i * 8 + (tid >> 5);
    int r0 = (tid & 31) * 2;
    unsigned int pk = (unsigned int)f2bf(tile[r0][c]) |
                      ((unsigned int)f2bf(tile[r0 + 1][c]) << 16);
    *(unsigned int*)(dst + (size_t)(tc * 64 + c) * R + tr * 64 + r0) = pk;
  }
}

// ---------------- main fused kernel ----------------
// W1t: bf16 [E][DH][DIN]  (c-major: A-frag of phase-1 = contiguous 16B in k)
// W2t: bf16 [E][DOUT][DH] (n-major: A-frag of phase-2 = contiguous 16B in c)

// stage one chunk (expert e, hidden-col block hc): W1c 64x128 (16KB) + W2c 128x64 (16KB)
// LDS linear dest, global source pre-swizzled so that READS with byte^=((row&7)<<4)
// are bank-conflict-free (G21: both-sides-or-neither).
__device__ __forceinline__ void stage_chunk(
    const unsigned short* __restrict__ W1t, const unsigned short* __restrict__ W2t,
    unsigned char* buf, int t, int tid, int wv)
{
  const int e = t >> 2, hc = t & 3;
  const unsigned char* w1b =
      (const unsigned char*)(W1t + (size_t)(e * DH_ + hc * 64) * DIN_);
  #pragma unroll
  for (int r = 0; r < 2; ++r) {
    const int o  = (r * 512 + tid) * 16;
    const int c  = o >> 8;                       // 0..63, row stride 256B
    const int ko = (o & 255) ^ ((c & 7) << 4);   // inverse-swizzled source col
    gload_lds16(w1b + c * 256 + ko, buf + r * 8192 + wv * 1024);
  }
  const unsigned char* w2b = (const unsigned char*)W2t;
  #pragma unroll
  for (int r = 0; r < 2; ++r) {
    const int o  = (r * 512 + tid) * 16;
    const int n  = o >> 7;                       // 0..127, row stride 128B
    const int co = (o & 127) ^ ((n & 7) << 4);
    gload_lds16(w2b + (size_t)(e * DOUT_ + n) * 512 + hc * 128 + co,
                buf + 16384 + r * 8192 + wv * 1024);
  }
}

__global__ __launch_bounds__(512, 2) void moe_main(
    const float* __restrict__ x, const float* __restrict__ wts,
    const float* __restrict__ b1, const float* __restrict__ b2,
    const unsigned short* __restrict__ W1t, const unsigned short* __restrict__ W2t,
    float* __restrict__ out)
{
  __shared__ __align__(16) unsigned char Wbuf[2][32768]; // dbuf: W1c(16K)+W2c(16K)
  __shared__ __align__(16) unsigned char hbuf[32768];    // H tile [256 m][64 c] bf16, swizzled
  __shared__ float wls[E_ * BM_];                        // wls[e*256+m] = weights[bm+m][e]

  const int tid  = threadIdx.x;
  const int lane = tid & 63;
  const int wv   = tid >> 6;       // 0..7
  const int q    = lane >> 4;      // quarter 0..3
  const int l16  = lane & 15;
  const int swz  = (l16 & 7) << 4; // row&7 == l16&7 for every frag row we touch
  const long bm  = (long)blockIdx.x * BM_;

  const int m_half = (wv >> 1) * 64;  // this wave's 64 batch rows
  const int c_half = (wv & 1) * 32;   // phase-1: 32 of the 64 chunk h-cols
  const int n_half = (wv & 1) * 64;   // phase-2: 64 of the 128 out cols

  for (int i = tid; i < E_ * BM_; i += 512) {
    int e = i >> 8, m = i & 255;
    wls[i] = wts[(bm + m) * E_ + e];
  }

  // kick off chunk-0 weight staging early (drained by first loop barrier)
  stage_chunk(W1t, W2t, Wbuf[0], 0, tid, wv);

  // hoist this wave's x fragments to registers (B-operand of phase-1, reused 32x)
  // B[k][m]: lane -> x[m_half+mf*16+l16][ks*32+q*8 .. +8)
  bf16x8 xf[4][4];
  #pragma unroll
  for (int mf = 0; mf < 4; ++mf) {
    const float* xr = x + (bm + m_half + mf * 16 + l16) * DIN_;
    #pragma unroll
    for (int ks = 0; ks < 4; ++ks) {
      int k0 = ks * 32 + q * 8;
      float4 lo = *(const float4*)(xr + k0);
      float4 hi = *(const float4*)(xr + k0 + 4);
      bf16x8 f;
      f[0] = (short)f2bf(lo.x); f[1] = (short)f2bf(lo.y);
      f[2] = (short)f2bf(lo.z); f[3] = (short)f2bf(lo.w);
      f[4] = (short)f2bf(hi.x); f[5] = (short)f2bf(hi.y);
      f[6] = (short)f2bf(hi.z); f[7] = (short)f2bf(hi.w);
      xf[mf][ks] = f;
    }
  }

  f32x4 oacc[4][4];   // outT frags: [nf][mf], 64 f32/lane
  #pragma unroll
  for (int i = 0; i < 4; ++i)
    #pragma unroll
    for (int j = 0; j < 4; ++j) oacc[i][j] = 0.0f;

  for (int t = 0; t < 32; ++t) {             // chunk = (expert e, hc block of 64 h-cols)
    const int e = t >> 2, hc = t & 3;
    unsigned char* Wc = Wbuf[t & 1];
    __syncthreads();                         // Wbuf[t&1] staged, hbuf free
    if (t + 1 < 32) stage_chunk(W1t, W2t, Wbuf[(t + 1) & 1], t + 1, tid, wv);

    float wreg[4];
    #pragma unroll
    for (int mf = 0; mf < 4; ++mf) wreg[mf] = wls[e * 256 + m_half + mf * 16 + l16];

    // ---- phase 1: Hc^T[c][m] = sum_k W1t[c][k] * x[m][k], K=128
    f32x4 hacc[2][4];
    #pragma unroll
    for (int i = 0; i < 2; ++i)
      #pragma unroll
      for (int j = 0; j < 4; ++j) hacc[i][j] = 0.0f;

    #pragma unroll
    for (int ks = 0; ks < 4; ++ks) {
      const int kb = ks * 64 + q * 16;       // byte offset of 16B k-frag in 256B row
      bf16x8 a0 = *(const bf16x8*)(Wc + (c_half +      l16) * 256 + (kb ^ swz));
      bf16x8 a1 = *(const bf16x8*)(Wc + (c_half + 16 + l16) * 256 + (kb ^ swz));
      #pragma unroll
      for (int mf = 0; mf < 4; ++mf) {
        hacc[0][mf] = __builtin_amdgcn_mfma_f32_16x16x32_bf16(a0, xf[mf][ks], hacc[0][mf], 0, 0, 0);
        hacc[1][mf] = __builtin_amdgcn_mfma_f32_16x16x32_bf16(a1, xf[mf][ks], hacc[1][mf], 0, 0, 0);
      }
    }
    // bias + relu + fold w[b,e]; D-frag: c = c0+reg (4 consecutive), m = l16-mapped
    #pragma unroll
    for (int cf = 0; cf < 2; ++cf) {
      const int c0 = c_half + cf * 16 + q * 4;
      float4 bb = *(const float4*)(b1 + e * DH_ + hc * 64 + c0);
      #pragma unroll
      for (int mf = 0; mf < 4; ++mf) {
        const int m = m_half + mf * 16 + l16;
        f32x4 v = hacc[cf][mf];
        const float w = wreg[mf];
        float h0 = fmaxf(v[0] + bb.x, 0.0f) * w;
        float h1 = fmaxf(v[1] + bb.y, 0.0f) * w;
        float h2 = fmaxf(v[2] + bb.z, 0.0f) * w;
        float h3 = fmaxf(v[3] + bb.w, 0.0f) * w;
        uint2 pk;
        pk.x = (unsigned int)f2bf(h0) | ((unsigned int)f2bf(h1) << 16);
        pk.y = (unsigned int)f2bf(h2) | ((unsigned int)f2bf(h3) << 16);
        *(uint2*)(hbuf + m * 128 + ((c0 * 2) ^ swz)) = pk;
      }
    }
    __syncthreads();                         // hbuf ready for all waves

    // ---- phase 2: out^T[n][m] += sum_c W2t[n][c] * H[m][c], K=64
    const unsigned char* W2c = Wc + 16384;
    #pragma unroll
    for (int ks = 0; ks < 2; ++ks) {
      const int clb = ks * 64 + q * 16;
      bf16x8 a2[4], bh[4];
      #pragma unroll
      for (int nf = 0; nf < 4; ++nf)
        a2[nf] = *(const bf16x8*)(W2c + (n_half + nf * 16 + l16) * 128 + (clb ^ swz));
      #pragma unroll
      for (int mf = 0; mf < 4; ++mf)
        bh[mf] = *(const bf16x8*)(hbuf + (m_half + mf * 16 + l16) * 128 + (clb ^ swz));
      #pragma unroll
      for (int nf = 0; nf < 4; ++nf)
        #pragma unroll
        for (int mf = 0; mf < 4; ++mf)
          oacc[nf][mf] = __builtin_amdgcn_mfma_f32_16x16x32_bf16(a2[nf], bh[mf], oacc[nf][mf], 0, 0, 0);
    }
  }

  // ---- epilogue: out[m][n] = oacc^T + sum_e w[m][e]*b2[e][n]; 16B stores
  #pragma unroll
  for (int nf = 0; nf < 4; ++nf) {
    const int n0 = n_half + nf * 16 + q * 4;
    #pragma unroll
    for (int mf = 0; mf < 4; ++mf) {
      const int m = m_half + mf * 16 + l16;
      f32x4 v = oacc[nf][mf];
      #pragma unroll
      for (int e = 0; e < E_; ++e) {
        const float w = wls[e * 256 + m];
        float4 bb = *(const float4*)(b2 + e * DOUT_ + n0);
        v[0] += w * bb.x; v[1] += w * bb.y; v[2] += w * bb.z; v[3] += w * bb.w;
      }
      float4 o; o.x = v[0]; o.y = v[1]; o.z = v[2]; o.w = v[3];
      *(float4*)(out + (bm + m) * DOUT_ + n0) = o;
    }
  }
}

extern "C" void kernel_launch(void* const* d_in, const int* in_sizes, int n_in,
                              void* d_out, int out_size, void* d_ws, size_t ws_size,
                              hipStream_t stream) {
  const float* x   = (const float*)d_in[0];
  const float* wts = (const float*)d_in[1];
  const float* W1  = (const float*)d_in[2];
  const float* b1  = (const float*)d_in[3];
  const float* W2  = (const float*)d_in[4];
  const float* b2  = (const float*)d_in[5];
  float* out = (float*)d_out;

  unsigned short* W1t = (unsigned short*)d_ws;            // bf16 [8][256][128] = 512KB
  unsigned short* W2t = W1t + (size_t)E_ * DH_ * DIN_;    // bf16 [8][128][256] = 512KB

  // W1 [8][128][256] -> W1t [8][256][128]
  transpose_to_bf16<<<64, 256, 0, stream>>>(W1, W1t, 128, 256, 2, 4);
  // W2 [8][256][128] -> W2t [8][128][256]
  transpose_to_bf16<<<64, 256, 0, stream>>>(W2, W2t, 256, 128, 4, 2);

  moe_main<<<65536 / BM_, 512, 0, stream>>>(x, wts, b1, b2, W1t, W2t, out);
}

// Round 3
// 93.820 us; speedup vs baseline: 1.2141x; 1.2141x over previous
//
#include <hip/hip_runtime.h>

// MoE all-experts dense MLP, fused bf16-MFMA kernel (32x32x16 + T12 in-reg H).
// E=8, D_IN=128, D_HID=256, D_OUT=128, B=65536. Out f32 [B,128].

#define E_    8
#define DIN_  128
#define DH_   256
#define DOUT_ 128
#define BM_   128   // batch rows per block (4 waves x 32 rows)
#define NCHUNK 32   // 8 experts x 4 hidden-col blocks of 64

typedef __attribute__((ext_vector_type(8))) short bf16x8;   // MFMA A/B frag (4 VGPR)
typedef __attribute__((ext_vector_type(16))) float f32x16;  // 32x32 MFMA C/D frag
typedef __attribute__((ext_vector_type(2))) unsigned int uint2v;

__device__ __forceinline__ unsigned short f2bf(float f) {
  union { float f; unsigned int u; } v; v.f = f;
  unsigned int u = v.u;
  u += 0x7fffu + ((u >> 16) & 1u);
  return (unsigned short)(u >> 16);
}

__device__ __forceinline__ unsigned int cvt_pk_bf16(float lo, float hi) {
  unsigned int r;
  asm("v_cvt_pk_bf16_f32 %0, %1, %2" : "=v"(r) : "v"(lo), "v"(hi));
  return r;
}

__device__ __forceinline__ bf16x8 pack4(unsigned int a, unsigned int b,
                                        unsigned int c, unsigned int d) {
  union { unsigned int u[4]; bf16x8 v; } t;
  t.u[0] = a; t.u[1] = b; t.u[2] = c; t.u[3] = d;
  return t.v;
}

__device__ __forceinline__ void gload_lds16(const void* g, void* l) {
  __builtin_amdgcn_global_load_lds(
      (const __attribute__((address_space(1))) unsigned int*)g,
      (__attribute__((address_space(3))) unsigned int*)l, 16, 0, 0);
}

// ---------------- prep: f32 [mats][R][C] -> bf16 [mats][C][R] ----------------
__global__ __launch_bounds__(256) void transpose_to_bf16(
    const float* __restrict__ in, unsigned short* __restrict__ out,
    int R, int C, int nTR, int nTC)
{
  __shared__ float tile[64][65];
  const int tiles = nTR * nTC;
  const int mat = blockIdx.x / tiles;
  const int tt  = blockIdx.x % tiles;
  const int tr = tt / nTC, tc = tt % nTC;
  const float* src = in + (size_t)mat * R * C;
  unsigned short* dst = out + (size_t)mat * R * C;
  const int tid = threadIdx.x;
  #pragma unroll
  for (int i = 0; i < 16; ++i) {
    int row = i * 4 + (tid >> 6);
    int col = tid & 63;
    tile[row][col] = src[(size_t)(tr * 64 + row) * C + tc * 64 + col];
  }
  __syncthreads();
  #pragma unroll
  for (int i = 0; i < 8; ++i) {
    int c  = i * 8 + (tid >> 5);
    int r0 = (tid & 31) * 2;
    unsigned int pk = (unsigned int)f2bf(tile[r0][c]) |
                      ((unsigned int)f2bf(tile[r0 + 1][c]) << 16);
    *(unsigned int*)(dst + (size_t)(tc * 64 + c) * R + tr * 64 + r0) = pk;
  }
}

// ---------------- staging ----------------
// Chunk t=(e,hc): W1c [64 c][128 k] bf16 (16KB) + W2c [128 n][64 c] bf16 (16KB).
// LDS dest linear; global source inverse-swizzled so reads with
// byte ^= ((row&7)<<4) are conflict-free (G21 both-sides-or-neither).
__device__ __forceinline__ void stage_chunk(
    const unsigned short* __restrict__ W1t, const unsigned short* __restrict__ W2t,
    unsigned char* buf, int t, int tid, int wv)
{
  const int e = t >> 2, hc = t & 3;
  const unsigned char* w1b =
      (const unsigned char*)(W1t + (size_t)(e * DH_ + hc * 64) * DIN_);
  #pragma unroll
  for (int r = 0; r < 4; ++r) {
    const int o  = (r * 256 + tid) * 16;         // 0..16K-1
    const int c  = o >> 8;                       // row (256B stride)
    const int ko = (o & 255) ^ ((c & 7) << 4);
    gload_lds16(w1b + c * 256 + ko, buf + r * 4096 + wv * 1024);
  }
  const unsigned char* w2b = (const unsigned char*)W2t;
  #pragma unroll
  for (int r = 0; r < 4; ++r) {
    const int o  = (r * 256 + tid) * 16;
    const int n  = o >> 7;                       // row (128B stride)
    const int co = (o & 127) ^ ((n & 7) << 4);
    gload_lds16(w2b + (size_t)(e * DOUT_ + n) * 512 + hc * 128 + co,
                buf + 16384 + r * 4096 + wv * 1024);
  }
}

// ---------------- main fused kernel ----------------
// W1t: bf16 [E][DH(c)][DIN(k)], W2t: bf16 [E][DOUT(n)][DH(c)].
// Per wave: owns 32 batch rows; full c-range per chunk; H stays in registers.
__global__ __launch_bounds__(256, 2) void moe_main(
    const float* __restrict__ x, const float* __restrict__ wts,
    const float* __restrict__ b1, const float* __restrict__ b2,
    const unsigned short* __restrict__ W1t, const unsigned short* __restrict__ W2t,
    float* __restrict__ out)
{
  __shared__ __align__(16) unsigned char Wbuf[2][32768];  // W dbuf only -> 64KB

  const int tid  = threadIdx.x;
  const int lane = tid & 63;
  const int wv   = tid >> 6;        // 0..3
  const int l32  = lane & 31;
  const int hi   = lane >> 5;       // 0/1
  const int swz  = (l32 & 7) << 4;
  const long bm  = (long)blockIdx.x * BM_;
  const int m    = wv * 32 + l32;   // this lane's batch row (local)

  // prefetch chunk 0 weights (drained by first loop barrier)
  stage_chunk(W1t, W2t, Wbuf[0], 0, tid, wv);

  // per-lane expert weights for row m
  float wreg[8];
  {
    float4 a = *(const float4*)(wts + (bm + m) * E_);
    float4 b = *(const float4*)(wts + (bm + m) * E_ + 4);
    wreg[0] = a.x; wreg[1] = a.y; wreg[2] = a.z; wreg[3] = a.w;
    wreg[4] = b.x; wreg[5] = b.y; wreg[6] = b.z; wreg[7] = b.w;
  }

  // x fragments (phase-1 B operand): col=m=l32, k = ks*16 + hi*8 + j
  bf16x8 xf[8];
  #pragma unroll
  for (int ks = 0; ks < 8; ++ks) {
    const float* xr = x + (bm + m) * DIN_ + ks * 16 + hi * 8;
    float4 a = *(const float4*)xr;
    float4 b = *(const float4*)(xr + 4);
    xf[ks] = pack4(cvt_pk_bf16(a.x, a.y), cvt_pk_bf16(a.z, a.w),
                   cvt_pk_bf16(b.x, b.y), cvt_pk_bf16(b.z, b.w));
  }

  f32x16 oacc[4];   // out D-frags: col=n=nf*32+l32, row=m_local(reg,hi)
  #pragma unroll
  for (int nf = 0; nf < 4; ++nf) oacc[nf] = 0.0f;

  for (int t = 0; t < NCHUNK; ++t) {
    const int e = t >> 2, hc = t & 3;
    const unsigned char* Wc = Wbuf[t & 1];
    __syncthreads();   // Wbuf[t&1] staged (vmcnt drained) + prior reads done

    // b1 values for this chunk, issued BEFORE the prefetch so the counted
    // vmcnt wait for them never drains the staging queue.
    float bb[2][16];
    #pragma unroll
    for (int cf = 0; cf < 2; ++cf)
      #pragma unroll
      for (int g = 0; g < 4; ++g) {
        float4 b = *(const float4*)(b1 + e * DH_ + hc * 64 + cf * 32 + g * 8 + hi * 4);
        bb[cf][4 * g + 0] = b.x; bb[cf][4 * g + 1] = b.y;
        bb[cf][4 * g + 2] = b.z; bb[cf][4 * g + 3] = b.w;
      }

    if (t + 1 < NCHUNK) stage_chunk(W1t, W2t, Wbuf[(t + 1) & 1], t + 1, tid, wv);

    // ---- phase 1: Hc^T[c][m] = sum_k W1c[c][k]*x[m][k]  (c=64, K=128)
    f32x16 hacc[2];
    hacc[0] = 0.0f; hacc[1] = 0.0f;
    #pragma unroll
    for (int ks = 0; ks < 8; ++ks) {
      const int kb = ks * 32 + hi * 16;
      #pragma unroll
      for (int cf = 0; cf < 2; ++cf) {
        bf16x8 a = *(const bf16x8*)(Wc + (cf * 32 + l32) * 256 + (kb ^ swz));
        hacc[cf] = __builtin_amdgcn_mfma_f32_32x32x16_bf16(a, xf[ks], hacc[cf], 0, 0, 0);
      }
    }

    // ---- bias + relu + fold w[m,e]; cvt_pk + permlane32_swap -> p2 A-frags
    // D reg r of hacc[cf]: c = cf*32 + (r&3) + 8*(r>>2) + 4*hi, col = m.
    const float w = wreg[e];
    bf16x8 hfr[4];   // A-frag for c-range [16*ks2, 16*ks2+16)
    #pragma unroll
    for (int cf = 0; cf < 2; ++cf) {
      unsigned int u[8];
      #pragma unroll
      for (int p = 0; p < 8; ++p) {
        float h0 = fmaxf(hacc[cf][2 * p]     + bb[cf][2 * p],     0.0f) * w;
        float h1 = fmaxf(hacc[cf][2 * p + 1] + bb[cf][2 * p + 1], 0.0f) * w;
        u[p] = cvt_pk_bf16(h0, h1);
      }
      // swap(u0,u2) -> words (w0,w2); swap(u1,u3) -> (w1,w3)  [T12]
      uint2v s02 = __builtin_amdgcn_permlane32_swap(u[0], u[2], false, false);
      uint2v s13 = __builtin_amdgcn_permlane32_swap(u[1], u[3], false, false);
      uint2v s46 = __builtin_amdgcn_permlane32_swap(u[4], u[6], false, false);
      uint2v s57 = __builtin_amdgcn_permlane32_swap(u[5], u[7], false, false);
      hfr[2 * cf]     = pack4(s02[0], s13[0], s02[1], s13[1]);
      hfr[2 * cf + 1] = pack4(s46[0], s57[0], s46[1], s57[1]);
    }

    // ---- phase 2: out[m][n] += sum_c H[m][c]*W2c[n][c]  (A=H, B=W2 -> D col=n)
    #pragma unroll
    for (int ks = 0; ks < 4; ++ks) {
      const int cb = ks * 32 + hi * 16;
      #pragma unroll
      for (int nf = 0; nf < 4; ++nf) {
        bf16x8 b = *(const bf16x8*)(Wc + 16384 + (nf * 32 + l32) * 128 + (cb ^ swz));
        oacc[nf] = __builtin_amdgcn_mfma_f32_32x32x16_bf16(hfr[ks], b, oacc[nf], 0, 0, 0);
      }
    }
  }

  // ---- epilogue: fold Sigma_e w[m][e]*b2[e][n] via one rank-8 MFMA per nf.
  // A[m][k]: row = l32 (exactly wreg's row), k=e<8 -> w, k>=8 -> 0.
  // B[k][n]: col = l32, k=e<8 -> b2[e][n], else 0. Both placed with the same
  // k-map as every other MFMA here -> permutation-invariant pairing.
  const unsigned int z = 0;
  bf16x8 wfrag = pack4(hi ? z : cvt_pk_bf16(wreg[0], wreg[1]),
                       hi ? z : cvt_pk_bf16(wreg[2], wreg[3]),
                       hi ? z : cvt_pk_bf16(wreg[4], wreg[5]),
                       hi ? z : cvt_pk_bf16(wreg[6], wreg[7]));
  #pragma unroll
  for (int nf = 0; nf < 4; ++nf) {
    const float* bp = b2 + nf * 32 + l32;
    bf16x8 bfrag = pack4(
        hi ? z : cvt_pk_bf16(bp[0 * DOUT_], bp[1 * DOUT_]),
        hi ? z : cvt_pk_bf16(bp[2 * DOUT_], bp[3 * DOUT_]),
        hi ? z : cvt_pk_bf16(bp[4 * DOUT_], bp[5 * DOUT_]),
        hi ? z : cvt_pk_bf16(bp[6 * DOUT_], bp[7 * DOUT_]));
    oacc[nf] = __builtin_amdgcn_mfma_f32_32x32x16_bf16(wfrag, bfrag, oacc[nf], 0, 0, 0);
  }

  // ---- store: out[m][n], n = nf*32+l32, m row per reg mapping
  #pragma unroll
  for (int nf = 0; nf < 4; ++nf) {
    #pragma unroll
    for (int r = 0; r < 16; ++r) {
      const int mloc = (r & 3) + 8 * (r >> 2) + 4 * hi;
      out[(bm + wv * 32 + mloc) * DOUT_ + nf * 32 + l32] = oacc[nf][r];
    }
  }
}

extern "C" void kernel_launch(void* const* d_in, const int* in_sizes, int n_in,
                              void* d_out, int out_size, void* d_ws, size_t ws_size,
                              hipStream_t stream) {
  const float* x   = (const float*)d_in[0];
  const float* wts = (const float*)d_in[1];
  const float* W1  = (const float*)d_in[2];
  const float* b1  = (const float*)d_in[3];
  const float* W2  = (const float*)d_in[4];
  const float* b2  = (const float*)d_in[5];
  float* out = (float*)d_out;

  unsigned short* W1t = (unsigned short*)d_ws;            // bf16 [8][256][128]
  unsigned short* W2t = W1t + (size_t)E_ * DH_ * DIN_;    // bf16 [8][128][256]

  transpose_to_bf16<<<64, 256, 0, stream>>>(W1, W1t, 128, 256, 2, 4);
  transpose_to_bf16<<<64, 256, 0, stream>>>(W2, W2t, 256, 128, 4, 2);

  moe_main<<<65536 / BM_, 256, 0, stream>>>(x, wts, b1, b2, W1t, W2t, out);
}